// Round 1
// baseline (873.278 us; speedup 1.0000x reference)
//
#include <hip/hip_runtime.h>
#include <hip/hip_bf16.h>

typedef __bf16 bf16x8 __attribute__((ext_vector_type(8)));
typedef float f32x4 __attribute__((ext_vector_type(4)));
typedef unsigned short u16;

constexpr int BATCH = 2, SEQ = 2048, DM = 2048, NH = 16, HD = 128;
constexpr int N3 = 3 * DM;          // 6144
constexpr int MROWS = BATCH * SEQ;  // 4096

__device__ __forceinline__ u16 f2bf(float f) {
  unsigned u = __builtin_bit_cast(unsigned, f);
  unsigned r = 0x7FFFu + ((u >> 16) & 1u);
  return (u16)((u + r) >> 16);
}

// ---------------- convert f32 -> bf16 (n4 = n/4 float4 groups) ----------------
__global__ __launch_bounds__(256) void k_cvt(const float* __restrict__ in,
                                             u16* __restrict__ out, int n4) {
  int i = blockIdx.x * blockDim.x + threadIdx.x;
  if (i >= n4) return;
  float4 v = reinterpret_cast<const float4*>(in)[i];
  ushort4 o;
  o.x = f2bf(v.x); o.y = f2bf(v.y); o.z = f2bf(v.z); o.w = f2bf(v.w);
  reinterpret_cast<ushort4*>(out)[i] = o;
}

// ---------------- transpose f32 [K][N] -> bf16 [N][K] ----------------
__global__ __launch_bounds__(256) void k_transpose(const float* __restrict__ in,
                                                   u16* __restrict__ out, int K, int N) {
  __shared__ float tile[32][33];
  int n0 = blockIdx.x * 32, k0 = blockIdx.y * 32;
  int tx = threadIdx.x & 31, ty = threadIdx.x >> 5;  // 32 x 8
#pragma unroll
  for (int r = ty; r < 32; r += 8) tile[r][tx] = in[(long)(k0 + r) * N + n0 + tx];
  __syncthreads();
#pragma unroll
  for (int r = ty; r < 32; r += 8) out[(long)(n0 + r) * K + k0 + tx] = f2bf(tile[tx][r]);
}

// ---------------- QKV GEMM: C = A[M][K] * Bt[N][K]^T + bias; scatter to Q,K,Vt ----------------
__global__ __launch_bounds__(256) void k_gemm_qkv(const u16* __restrict__ A,
                                                  const u16* __restrict__ Bt,
                                                  const float* __restrict__ bias,
                                                  u16* __restrict__ Qb, u16* __restrict__ Kb,
                                                  u16* __restrict__ Vt) {
  constexpr int K = DM;
  __shared__ u16 As[128 * 32], Bs[128 * 32];
  int m0 = blockIdx.y * 128, n0 = blockIdx.x * 128;
  int t = threadIdx.x, lane = t & 63, w = t >> 6;
  int l15 = lane & 15, lhi = lane >> 4;
  int wr = (w >> 1) * 64, wc = (w & 1) * 64;
  int srow = t >> 2, sk = (t & 3) * 8;
  const u16* Ap0 = A + (long)(m0 + srow) * K + sk;
  const u16* Ap1 = A + (long)(m0 + 64 + srow) * K + sk;
  const u16* Bp0 = Bt + (long)(n0 + srow) * K + sk;
  const u16* Bp1 = Bt + (long)(n0 + 64 + srow) * K + sk;
  u16* As0 = As + srow * 32 + sk; u16* As1 = As0 + 64 * 32;
  u16* Bs0 = Bs + srow * 32 + sk; u16* Bs1 = Bs0 + 64 * 32;

  f32x4 acc[4][4] = {};
  for (int k0 = 0; k0 < K; k0 += 32) {
    bf16x8 a0 = *(const bf16x8*)(Ap0 + k0);
    bf16x8 a1 = *(const bf16x8*)(Ap1 + k0);
    bf16x8 b0 = *(const bf16x8*)(Bp0 + k0);
    bf16x8 b1 = *(const bf16x8*)(Bp1 + k0);
    __syncthreads();
    *(bf16x8*)As0 = a0; *(bf16x8*)As1 = a1;
    *(bf16x8*)Bs0 = b0; *(bf16x8*)Bs1 = b1;
    __syncthreads();
    bf16x8 af[4], bg[4];
#pragma unroll
    for (int i = 0; i < 4; i++) af[i] = *(const bf16x8*)(As + (wr + i * 16 + l15) * 32 + lhi * 8);
#pragma unroll
    for (int j = 0; j < 4; j++) bg[j] = *(const bf16x8*)(Bs + (wc + j * 16 + l15) * 32 + lhi * 8);
#pragma unroll
    for (int i = 0; i < 4; i++)
#pragma unroll
      for (int j = 0; j < 4; j++)
        acc[i][j] = __builtin_amdgcn_mfma_f32_16x16x32_bf16(af[i], bg[j], acc[i][j], 0, 0, 0);
  }
#pragma unroll
  for (int i = 0; i < 4; i++)
#pragma unroll
    for (int j = 0; j < 4; j++) {
      int col = n0 + wc + j * 16 + l15;
      float bv = bias[col];
      int sec = col >> 11, dn = col & 2047, h = dn >> 7, hd = dn & 127;
#pragma unroll
      for (int r = 0; r < 4; r++) {
        int row = m0 + wr + i * 16 + lhi * 4 + r;
        int bb = row >> 11, ss = row & 2047;
        u16 val = f2bf(acc[i][j][r] + bv);
        if (sec == 0)
          Qb[(((long)(bb * NH + h)) * SEQ + ss) * HD + hd] = val;
        else if (sec == 1)
          Kb[(((long)(bb * NH + h)) * SEQ + ss) * HD + hd] = val;
        else
          Vt[(((long)(bb * NH + h)) * HD + hd) * SEQ + ss] = val;
      }
    }
}

// ---------------- output GEMM: out = A[M][K] * Bt[N][K]^T + bias (f32 out) ----------------
__global__ __launch_bounds__(256) void k_gemm_out(const u16* __restrict__ A,
                                                  const u16* __restrict__ Bt,
                                                  const float* __restrict__ bias,
                                                  float* __restrict__ Out) {
  constexpr int K = DM, N = DM;
  __shared__ u16 As[128 * 32], Bs[128 * 32];
  int m0 = blockIdx.y * 128, n0 = blockIdx.x * 128;
  int t = threadIdx.x, lane = t & 63, w = t >> 6;
  int l15 = lane & 15, lhi = lane >> 4;
  int wr = (w >> 1) * 64, wc = (w & 1) * 64;
  int srow = t >> 2, sk = (t & 3) * 8;
  const u16* Ap0 = A + (long)(m0 + srow) * K + sk;
  const u16* Ap1 = A + (long)(m0 + 64 + srow) * K + sk;
  const u16* Bp0 = Bt + (long)(n0 + srow) * K + sk;
  const u16* Bp1 = Bt + (long)(n0 + 64 + srow) * K + sk;
  u16* As0 = As + srow * 32 + sk; u16* As1 = As0 + 64 * 32;
  u16* Bs0 = Bs + srow * 32 + sk; u16* Bs1 = Bs0 + 64 * 32;

  f32x4 acc[4][4] = {};
  for (int k0 = 0; k0 < K; k0 += 32) {
    bf16x8 a0 = *(const bf16x8*)(Ap0 + k0);
    bf16x8 a1 = *(const bf16x8*)(Ap1 + k0);
    bf16x8 b0 = *(const bf16x8*)(Bp0 + k0);
    bf16x8 b1 = *(const bf16x8*)(Bp1 + k0);
    __syncthreads();
    *(bf16x8*)As0 = a0; *(bf16x8*)As1 = a1;
    *(bf16x8*)Bs0 = b0; *(bf16x8*)Bs1 = b1;
    __syncthreads();
    bf16x8 af[4], bg[4];
#pragma unroll
    for (int i = 0; i < 4; i++) af[i] = *(const bf16x8*)(As + (wr + i * 16 + l15) * 32 + lhi * 8);
#pragma unroll
    for (int j = 0; j < 4; j++) bg[j] = *(const bf16x8*)(Bs + (wc + j * 16 + l15) * 32 + lhi * 8);
#pragma unroll
    for (int i = 0; i < 4; i++)
#pragma unroll
      for (int j = 0; j < 4; j++)
        acc[i][j] = __builtin_amdgcn_mfma_f32_16x16x32_bf16(af[i], bg[j], acc[i][j], 0, 0, 0);
  }
#pragma unroll
  for (int i = 0; i < 4; i++)
#pragma unroll
    for (int j = 0; j < 4; j++) {
      int col = n0 + wc + j * 16 + l15;
      float bv = bias[col];
#pragma unroll
      for (int r = 0; r < 4; r++) {
        int row = m0 + wr + i * 16 + lhi * 4 + r;
        Out[(long)row * N + col] = acc[i][j][r] + bv;
      }
    }
}

// ---------------- flash attention (causal + alibi) ----------------
// Qb,Kb: [B*H][S][HD] bf16; Vt: [B*H][HD][S] bf16; mask: [H][S] f32; Ao: [B*S][DM] bf16
__global__ __launch_bounds__(256) void k_attn(const u16* __restrict__ Qb,
                                              const u16* __restrict__ Kb,
                                              const u16* __restrict__ Vt,
                                              const float* __restrict__ mask,
                                              u16* __restrict__ Ao) {
  int bh = blockIdx.y;  // b*NH + h
  int qt = blockIdx.x;
  int t = threadIdx.x, w = t >> 6, lane = t & 63;
  int l15 = lane & 15, lhi = lane >> 4;
  int q0 = qt * 64 + w * 16;
  int b = bh >> 4, h = bh & 15;
  const u16* Qh = Qb + (long)bh * SEQ * HD;
  const u16* Kh = Kb + (long)bh * SEQ * HD;
  const u16* Vh = Vt + (long)bh * HD * SEQ;
  const float* mh = mask + h * SEQ;

  __shared__ u16 p_lds[4 * 16 * 32];
  u16* pw = p_lds + w * (16 * 32);

  bf16x8 qf[4];
#pragma unroll
  for (int kc = 0; kc < 4; kc++)
    qf[kc] = *(const bf16x8*)(Qh + (long)(q0 + l15) * HD + kc * 32 + lhi * 8);

  float mrun[4], lrun[4];
  f32x4 oacc[8] = {};
#pragma unroll
  for (int r = 0; r < 4; r++) { mrun[r] = -1e30f; lrun[r] = 0.f; }

  const float sm_scale = 0.08838834764831845f;  // 1/sqrt(128)
  int nt = qt * 2 + 2;  // 32-key tiles covering keys < (qt+1)*64
  for (int kt = 0; kt < nt; kt++) {
    int kb = kt * 32;
    f32x4 sc[2] = {};
#pragma unroll
    for (int cb = 0; cb < 2; cb++)
#pragma unroll
      for (int kc = 0; kc < 4; kc++) {
        bf16x8 kf = *(const bf16x8*)(Kh + (long)(kb + cb * 16 + l15) * HD + kc * 32 + lhi * 8);
        sc[cb] = __builtin_amdgcn_mfma_f32_16x16x32_bf16(qf[kc], kf, sc[cb], 0, 0, 0);
      }
    float p[2][4], tmax[4];
#pragma unroll
    for (int r = 0; r < 4; r++) tmax[r] = -1e30f;
#pragma unroll
    for (int cb = 0; cb < 2; cb++) {
      int col = kb + cb * 16 + l15;
      float bv = mh[col];
#pragma unroll
      for (int r = 0; r < 4; r++) {
        int row = q0 + lhi * 4 + r;
        float v = (col <= row) ? sc[cb][r] * sm_scale + bv : -1e30f;
        p[cb][r] = v;
        tmax[r] = fmaxf(tmax[r], v);
      }
    }
    float alpha[4];
#pragma unroll
    for (int r = 0; r < 4; r++) {
      float v = tmax[r];
      v = fmaxf(v, __shfl_xor(v, 1));
      v = fmaxf(v, __shfl_xor(v, 2));
      v = fmaxf(v, __shfl_xor(v, 4));
      v = fmaxf(v, __shfl_xor(v, 8));
      float mnew = fmaxf(mrun[r], v);
      alpha[r] = expf(mrun[r] - mnew);  // 0 when mrun=-1e30 & mnew real; 1 when both -1e30 (lrun=0)
      mrun[r] = mnew;
      float s = 0.f;
#pragma unroll
      for (int cb = 0; cb < 2; cb++) {
        float e = expf(p[cb][r] - mnew);  // masked -> expf(-huge) = 0
        p[cb][r] = e;
        s += e;
      }
      s += __shfl_xor(s, 1); s += __shfl_xor(s, 2);
      s += __shfl_xor(s, 4); s += __shfl_xor(s, 8);
      lrun[r] = lrun[r] * alpha[r] + s;
    }
#pragma unroll
    for (int nb = 0; nb < 8; nb++)
#pragma unroll
      for (int r = 0; r < 4; r++) oacc[nb][r] *= alpha[r];
#pragma unroll
    for (int cb = 0; cb < 2; cb++)
#pragma unroll
      for (int r = 0; r < 4; r++)
        pw[(lhi * 4 + r) * 32 + cb * 16 + l15] = f2bf(p[cb][r]);
    __syncthreads();
    bf16x8 pa = *(const bf16x8*)(pw + l15 * 32 + lhi * 8);
#pragma unroll
    for (int nb = 0; nb < 8; nb++) {
      bf16x8 vf = *(const bf16x8*)(Vh + (long)(nb * 16 + l15) * SEQ + kb + lhi * 8);
      oacc[nb] = __builtin_amdgcn_mfma_f32_16x16x32_bf16(pa, vf, oacc[nb], 0, 0, 0);
    }
    __syncthreads();
  }
#pragma unroll
  for (int nb = 0; nb < 8; nb++)
#pragma unroll
    for (int r = 0; r < 4; r++) {
      int row = q0 + lhi * 4 + r;
      float v = oacc[nb][r] / lrun[r];
      Ao[((long)(b * SEQ + row)) * DM + h * HD + nb * 16 + l15] = f2bf(v);
    }
}

// ---------------- launcher ----------------
extern "C" void kernel_launch(void* const* d_in, const int* in_sizes, int n_in,
                              void* d_out, int out_size, void* d_ws, size_t ws_size,
                              hipStream_t stream) {
  const float* x    = (const float*)d_in[0];
  const float* amsk = (const float*)d_in[1];
  const float* Wqkv = (const float*)d_in[2];
  const float* bqkv = (const float*)d_in[3];
  const float* Wout = (const float*)d_in[4];
  const float* bout = (const float*)d_in[5];
  float* out = (float*)d_out;

  // workspace layout (bf16 buffers), total ~112 MB
  char* ws = (char*)d_ws;
  u16* xb  = (u16*)(ws + 0);                   // [4096][2048]
  u16* WqT = (u16*)(ws + 16777216UL);          // [6144][2048]
  u16* WoT = (u16*)(ws + 41943040UL);          // [2048][2048]
  u16* Qb  = (u16*)(ws + 50331648UL);          // [B*H][S][HD]
  u16* Kb  = (u16*)(ws + 67108864UL);          // [B*H][S][HD]
  u16* Vt  = (u16*)(ws + 83886080UL);          // [B*H][HD][S]
  u16* Ao  = (u16*)(ws + 100663296UL);         // [4096][2048]

  k_cvt<<<8192, 256, 0, stream>>>(x, xb, (MROWS * DM) / 4);
  k_transpose<<<dim3(N3 / 32, DM / 32), 256, 0, stream>>>(Wqkv, WqT, DM, N3);
  k_transpose<<<dim3(DM / 32, DM / 32), 256, 0, stream>>>(Wout, WoT, DM, DM);
  k_gemm_qkv<<<dim3(N3 / 128, MROWS / 128), 256, 0, stream>>>(xb, WqT, bqkv, Qb, Kb, Vt);
  k_attn<<<dim3(SEQ / 64, BATCH * NH), 256, 0, stream>>>(Qb, Kb, Vt, amsk, Ao);
  k_gemm_out<<<dim3(DM / 128, MROWS / 128), 256, 0, stream>>>(Ao, WoT, bout, out);
}

// Round 2
// 765.713 us; speedup vs baseline: 1.1405x; 1.1405x over previous
//
#include <hip/hip_runtime.h>
#include <hip/hip_bf16.h>

typedef __bf16 bf16x8 __attribute__((ext_vector_type(8)));
typedef float f32x4 __attribute__((ext_vector_type(4)));
typedef unsigned short u16;

constexpr int BATCH = 2, SEQ = 2048, DM = 2048, NH = 16, HD = 128;
constexpr int N3 = 3 * DM;          // 6144
constexpr int MROWS = BATCH * SEQ;  // 4096

__device__ __forceinline__ u16 f2bf(float f) {
  unsigned u = __builtin_bit_cast(unsigned, f);
  unsigned r = 0x7FFFu + ((u >> 16) & 1u);
  return (u16)((u + r) >> 16);
}

// ---------------- convert f32 -> bf16 (n4 = n/4 float4 groups) ----------------
__global__ __launch_bounds__(256) void k_cvt(const float* __restrict__ in,
                                             u16* __restrict__ out, int n4) {
  int i = blockIdx.x * blockDim.x + threadIdx.x;
  if (i >= n4) return;
  float4 v = reinterpret_cast<const float4*>(in)[i];
  ushort4 o;
  o.x = f2bf(v.x); o.y = f2bf(v.y); o.z = f2bf(v.z); o.w = f2bf(v.w);
  reinterpret_cast<ushort4*>(out)[i] = o;
}

// ---------------- transpose f32 [K][N] -> bf16 [N][K] ----------------
__global__ __launch_bounds__(256) void k_transpose(const float* __restrict__ in,
                                                   u16* __restrict__ out, int K, int N) {
  __shared__ float tile[32][33];
  int n0 = blockIdx.x * 32, k0 = blockIdx.y * 32;
  int tx = threadIdx.x & 31, ty = threadIdx.x >> 5;  // 32 x 8
#pragma unroll
  for (int r = ty; r < 32; r += 8) tile[r][tx] = in[(long)(k0 + r) * N + n0 + tx];
  __syncthreads();
#pragma unroll
  for (int r = ty; r < 32; r += 8) out[(long)(n0 + r) * K + k0 + tx] = f2bf(tile[tx][r]);
}

// ---------------- QKV GEMM: C = A[M][K] * Bt[N][K]^T + bias; scatter to Q,K,Vt ----------------
__global__ __launch_bounds__(256) void k_gemm_qkv(const u16* __restrict__ A,
                                                  const u16* __restrict__ Bt,
                                                  const float* __restrict__ bias,
                                                  u16* __restrict__ Qb, u16* __restrict__ Kb,
                                                  u16* __restrict__ Vt) {
  constexpr int K = DM;
  __shared__ u16 As[128 * 32], Bs[128 * 32];
  int m0 = blockIdx.y * 128, n0 = blockIdx.x * 128;
  int t = threadIdx.x, lane = t & 63, w = t >> 6;
  int l15 = lane & 15, lhi = lane >> 4;
  int wr = (w >> 1) * 64, wc = (w & 1) * 64;
  int srow = t >> 2, sk = (t & 3) * 8;
  const u16* Ap0 = A + (long)(m0 + srow) * K + sk;
  const u16* Ap1 = A + (long)(m0 + 64 + srow) * K + sk;
  const u16* Bp0 = Bt + (long)(n0 + srow) * K + sk;
  const u16* Bp1 = Bt + (long)(n0 + 64 + srow) * K + sk;
  u16* As0 = As + srow * 32 + sk; u16* As1 = As0 + 64 * 32;
  u16* Bs0 = Bs + srow * 32 + sk; u16* Bs1 = Bs0 + 64 * 32;

  f32x4 acc[4][4] = {};
  for (int k0 = 0; k0 < K; k0 += 32) {
    bf16x8 a0 = *(const bf16x8*)(Ap0 + k0);
    bf16x8 a1 = *(const bf16x8*)(Ap1 + k0);
    bf16x8 b0 = *(const bf16x8*)(Bp0 + k0);
    bf16x8 b1 = *(const bf16x8*)(Bp1 + k0);
    __syncthreads();
    *(bf16x8*)As0 = a0; *(bf16x8*)As1 = a1;
    *(bf16x8*)Bs0 = b0; *(bf16x8*)Bs1 = b1;
    __syncthreads();
    bf16x8 af[4], bg[4];
#pragma unroll
    for (int i = 0; i < 4; i++) af[i] = *(const bf16x8*)(As + (wr + i * 16 + l15) * 32 + lhi * 8);
#pragma unroll
    for (int j = 0; j < 4; j++) bg[j] = *(const bf16x8*)(Bs + (wc + j * 16 + l15) * 32 + lhi * 8);
#pragma unroll
    for (int i = 0; i < 4; i++)
#pragma unroll
      for (int j = 0; j < 4; j++)
        acc[i][j] = __builtin_amdgcn_mfma_f32_16x16x32_bf16(af[i], bg[j], acc[i][j], 0, 0, 0);
  }
#pragma unroll
  for (int i = 0; i < 4; i++)
#pragma unroll
    for (int j = 0; j < 4; j++) {
      int col = n0 + wc + j * 16 + l15;
      float bv = bias[col];
      int sec = col >> 11, dn = col & 2047, h = dn >> 7, hd = dn & 127;
#pragma unroll
      for (int r = 0; r < 4; r++) {
        int row = m0 + wr + i * 16 + lhi * 4 + r;
        int bb = row >> 11, ss = row & 2047;
        u16 val = f2bf(acc[i][j][r] + bv);
        if (sec == 0)
          Qb[(((long)(bb * NH + h)) * SEQ + ss) * HD + hd] = val;
        else if (sec == 1)
          Kb[(((long)(bb * NH + h)) * SEQ + ss) * HD + hd] = val;
        else
          Vt[(((long)(bb * NH + h)) * HD + hd) * SEQ + ss] = val;
      }
    }
}

// ---------------- output GEMM: out = A[M][K] * Bt[N][K]^T + bias (f32 out) ----------------
__global__ __launch_bounds__(256) void k_gemm_out(const u16* __restrict__ A,
                                                  const u16* __restrict__ Bt,
                                                  const float* __restrict__ bias,
                                                  float* __restrict__ Out) {
  constexpr int K = DM, N = DM;
  __shared__ u16 As[128 * 32], Bs[128 * 32];
  int m0 = blockIdx.y * 128, n0 = blockIdx.x * 128;
  int t = threadIdx.x, lane = t & 63, w = t >> 6;
  int l15 = lane & 15, lhi = lane >> 4;
  int wr = (w >> 1) * 64, wc = (w & 1) * 64;
  int srow = t >> 2, sk = (t & 3) * 8;
  const u16* Ap0 = A + (long)(m0 + srow) * K + sk;
  const u16* Ap1 = A + (long)(m0 + 64 + srow) * K + sk;
  const u16* Bp0 = Bt + (long)(n0 + srow) * K + sk;
  const u16* Bp1 = Bt + (long)(n0 + 64 + srow) * K + sk;
  u16* As0 = As + srow * 32 + sk; u16* As1 = As0 + 64 * 32;
  u16* Bs0 = Bs + srow * 32 + sk; u16* Bs1 = Bs0 + 64 * 32;

  f32x4 acc[4][4] = {};
  for (int k0 = 0; k0 < K; k0 += 32) {
    bf16x8 a0 = *(const bf16x8*)(Ap0 + k0);
    bf16x8 a1 = *(const bf16x8*)(Ap1 + k0);
    bf16x8 b0 = *(const bf16x8*)(Bp0 + k0);
    bf16x8 b1 = *(const bf16x8*)(Bp1 + k0);
    __syncthreads();
    *(bf16x8*)As0 = a0; *(bf16x8*)As1 = a1;
    *(bf16x8*)Bs0 = b0; *(bf16x8*)Bs1 = b1;
    __syncthreads();
    bf16x8 af[4], bg[4];
#pragma unroll
    for (int i = 0; i < 4; i++) af[i] = *(const bf16x8*)(As + (wr + i * 16 + l15) * 32 + lhi * 8);
#pragma unroll
    for (int j = 0; j < 4; j++) bg[j] = *(const bf16x8*)(Bs + (wc + j * 16 + l15) * 32 + lhi * 8);
#pragma unroll
    for (int i = 0; i < 4; i++)
#pragma unroll
      for (int j = 0; j < 4; j++)
        acc[i][j] = __builtin_amdgcn_mfma_f32_16x16x32_bf16(af[i], bg[j], acc[i][j], 0, 0, 0);
  }
#pragma unroll
  for (int i = 0; i < 4; i++)
#pragma unroll
    for (int j = 0; j < 4; j++) {
      int col = n0 + wc + j * 16 + l15;
      float bv = bias[col];
#pragma unroll
      for (int r = 0; r < 4; r++) {
        int row = m0 + wr + i * 16 + lhi * 4 + r;
        Out[(long)row * N + col] = acc[i][j][r] + bv;
      }
    }
}

// ---------------- flash attention (causal + alibi), KVBLK=64, no block barriers ----------------
// Qb,Kb: [B*H][S][HD] bf16; Vt: [B*H][HD][S] bf16; mask: [H][S] f32; Ao: [B*S][DM] bf16
__global__ __launch_bounds__(256) void k_attn(const u16* __restrict__ Qb,
                                              const u16* __restrict__ Kb,
                                              const u16* __restrict__ Vt,
                                              const float* __restrict__ mask,
                                              u16* __restrict__ Ao) {
  int bh = blockIdx.y;                       // b*NH + h
  int qt = (gridDim.x - 1) - blockIdx.x;     // longest blocks first (tail fix)
  int t = threadIdx.x, w = t >> 6, lane = t & 63;
  int l15 = lane & 15, lhi = lane >> 4;
  int q0 = qt * 64 + w * 16;
  int b = bh >> 4, h = bh & 15;
  const u16* Qh = Qb + (long)bh * SEQ * HD;
  const u16* Kh = Kb + (long)bh * SEQ * HD;
  const u16* Vh = Vt + (long)bh * HD * SEQ;
  const float* mh = mask + h * SEQ;

  // per-wave P buffer: [16 rows][64 cols] bf16, XOR-swizzled (idx ^ (row&7)<<3)
  __shared__ u16 p_lds[4 * 16 * 64];
  u16* pw = p_lds + w * (16 * 64);

  bf16x8 qf[4];
#pragma unroll
  for (int kc = 0; kc < 4; kc++)
    qf[kc] = *(const bf16x8*)(Qh + (long)(q0 + l15) * HD + kc * 32 + lhi * 8);

  int rowr[4];
#pragma unroll
  for (int r = 0; r < 4; r++) rowr[r] = q0 + lhi * 4 + r;

  float mrun[4], lrun[4];
  f32x4 oacc[8] = {};
#pragma unroll
  for (int r = 0; r < 4; r++) { mrun[r] = -1e30f; lrun[r] = 0.f; }

  const float sm_scale = 0.08838834764831845f;  // 1/sqrt(128)
  int nt = qt + 1;  // 64-key tiles covering keys <= qt*64+63
  for (int kt = 0; kt < nt; kt++) {
    int kb = kt * 64;
    bool diag = (kt == nt - 1);  // only the diagonal tile needs causal masking
    // ---- QK^T: scores for 16 rows x 64 cols ----
    f32x4 sc[4] = {};
#pragma unroll
    for (int kc = 0; kc < 4; kc++)
#pragma unroll
      for (int cb = 0; cb < 4; cb++) {
        bf16x8 kf = *(const bf16x8*)(Kh + (long)(kb + cb * 16 + l15) * HD + kc * 32 + lhi * 8);
        sc[cb] = __builtin_amdgcn_mfma_f32_16x16x32_bf16(qf[kc], kf, sc[cb], 0, 0, 0);
      }
    // ---- alibi + causal + running softmax ----
    float p[4][4], tmax[4];
#pragma unroll
    for (int r = 0; r < 4; r++) tmax[r] = -1e30f;
#pragma unroll
    for (int cb = 0; cb < 4; cb++) {
      int col = kb + cb * 16 + l15;
      float bv = mh[col];
#pragma unroll
      for (int r = 0; r < 4; r++) {
        float v = sc[cb][r] * sm_scale + bv;
        if (diag) v = (col <= rowr[r]) ? v : -1e30f;
        p[cb][r] = v;
        tmax[r] = fmaxf(tmax[r], v);
      }
    }
    float alpha[4];
#pragma unroll
    for (int r = 0; r < 4; r++) {
      float v = tmax[r];
      v = fmaxf(v, __shfl_xor(v, 1));
      v = fmaxf(v, __shfl_xor(v, 2));
      v = fmaxf(v, __shfl_xor(v, 4));
      v = fmaxf(v, __shfl_xor(v, 8));
      float mnew = fmaxf(mrun[r], v);
      alpha[r] = __expf(mrun[r] - mnew);
      mrun[r] = mnew;
      float s = 0.f;
#pragma unroll
      for (int cb = 0; cb < 4; cb++) {
        float e = __expf(p[cb][r] - mnew);
        p[cb][r] = e;
        s += e;
      }
      s += __shfl_xor(s, 1); s += __shfl_xor(s, 2);
      s += __shfl_xor(s, 4); s += __shfl_xor(s, 8);
      lrun[r] = lrun[r] * alpha[r] + s;
    }
#pragma unroll
    for (int nb = 0; nb < 8; nb++)
#pragma unroll
      for (int r = 0; r < 4; r++) oacc[nb][r] *= alpha[r];
    // ---- P -> LDS (swizzled), wave-local only: no block barrier needed ----
#pragma unroll
    for (int cb = 0; cb < 4; cb++)
#pragma unroll
      for (int r = 0; r < 4; r++) {
        int rr = lhi * 4 + r;
        pw[(rr * 64 + cb * 16 + l15) ^ ((rr & 7) << 3)] = f2bf(p[cb][r]);
      }
    asm volatile("s_waitcnt lgkmcnt(0)" ::: "memory");
    bf16x8 pa0 = *(const bf16x8*)(pw + ((l15 * 64 + lhi * 8) ^ ((l15 & 7) << 3)));
    bf16x8 pa1 = *(const bf16x8*)(pw + ((l15 * 64 + 32 + lhi * 8) ^ ((l15 & 7) << 3)));
    // ---- PV ----
#pragma unroll
    for (int nb = 0; nb < 8; nb++) {
      const u16* vbase = Vh + (long)(nb * 16 + l15) * SEQ + kb + lhi * 8;
      bf16x8 vf0 = *(const bf16x8*)(vbase);
      bf16x8 vf1 = *(const bf16x8*)(vbase + 32);
      oacc[nb] = __builtin_amdgcn_mfma_f32_16x16x32_bf16(pa0, vf0, oacc[nb], 0, 0, 0);
      oacc[nb] = __builtin_amdgcn_mfma_f32_16x16x32_bf16(pa1, vf1, oacc[nb], 0, 0, 0);
    }
  }
#pragma unroll
  for (int nb = 0; nb < 8; nb++)
#pragma unroll
    for (int r = 0; r < 4; r++) {
      int row = q0 + lhi * 4 + r;
      float v = oacc[nb][r] / lrun[r];
      Ao[((long)(b * SEQ + row)) * DM + h * HD + nb * 16 + l15] = f2bf(v);
    }
}

// ---------------- launcher ----------------
extern "C" void kernel_launch(void* const* d_in, const int* in_sizes, int n_in,
                              void* d_out, int out_size, void* d_ws, size_t ws_size,
                              hipStream_t stream) {
  const float* x    = (const float*)d_in[0];
  const float* amsk = (const float*)d_in[1];
  const float* Wqkv = (const float*)d_in[2];
  const float* bqkv = (const float*)d_in[3];
  const float* Wout = (const float*)d_in[4];
  const float* bout = (const float*)d_in[5];
  float* out = (float*)d_out;

  // workspace layout (bf16 buffers), total ~112 MB
  char* ws = (char*)d_ws;
  u16* xb  = (u16*)(ws + 0);                   // [4096][2048]
  u16* WqT = (u16*)(ws + 16777216UL);          // [6144][2048]
  u16* WoT = (u16*)(ws + 41943040UL);          // [2048][2048]
  u16* Qb  = (u16*)(ws + 50331648UL);          // [B*H][S][HD]
  u16* Kb  = (u16*)(ws + 67108864UL);          // [B*H][S][HD]
  u16* Vt  = (u16*)(ws + 83886080UL);          // [B*H][HD][S]
  u16* Ao  = (u16*)(ws + 100663296UL);         // [4096][2048]

  k_cvt<<<8192, 256, 0, stream>>>(x, xb, (MROWS * DM) / 4);
  k_transpose<<<dim3(N3 / 32, DM / 32), 256, 0, stream>>>(Wqkv, WqT, DM, N3);
  k_transpose<<<dim3(DM / 32, DM / 32), 256, 0, stream>>>(Wout, WoT, DM, DM);
  k_gemm_qkv<<<dim3(N3 / 128, MROWS / 128), 256, 0, stream>>>(xb, WqT, bqkv, Qb, Kb, Vt);
  k_attn<<<dim3(SEQ / 64, BATCH * NH), 256, 0, stream>>>(Qb, Kb, Vt, amsk, Ao);
  k_gemm_out<<<dim3(DM / 128, MROWS / 128), 256, 0, stream>>>(Ao, WoT, bout, out);
}

// Round 3
// 403.994 us; speedup vs baseline: 2.1616x; 1.8954x over previous
//
#include <hip/hip_runtime.h>
#include <hip/hip_bf16.h>

typedef __bf16 bf16x8 __attribute__((ext_vector_type(8)));
typedef float f32x4 __attribute__((ext_vector_type(4)));
typedef unsigned short u16;

constexpr int BATCH = 2, SEQ = 2048, DM = 2048, NH = 16, HD = 128;
constexpr int N3 = 3 * DM;          // 6144
constexpr int MROWS = BATCH * SEQ;  // 4096

__device__ __forceinline__ u16 f2bf(float f) {
  unsigned u = __builtin_bit_cast(unsigned, f);
  unsigned r = 0x7FFFu + ((u >> 16) & 1u);
  return (u16)((u + r) >> 16);
}

// ---------------- convert f32 -> bf16 (n4 = n/4 float4 groups) ----------------
__global__ __launch_bounds__(256) void k_cvt(const float* __restrict__ in,
                                             u16* __restrict__ out, int n4) {
  int i = blockIdx.x * blockDim.x + threadIdx.x;
  if (i >= n4) return;
  float4 v = reinterpret_cast<const float4*>(in)[i];
  ushort4 o;
  o.x = f2bf(v.x); o.y = f2bf(v.y); o.z = f2bf(v.z); o.w = f2bf(v.w);
  reinterpret_cast<ushort4*>(out)[i] = o;
}

// ---------------- transpose f32 [K][N] -> bf16 [N][K] ----------------
__global__ __launch_bounds__(256) void k_transpose(const float* __restrict__ in,
                                                   u16* __restrict__ out, int K, int N) {
  __shared__ float tile[32][33];
  int n0 = blockIdx.x * 32, k0 = blockIdx.y * 32;
  int tx = threadIdx.x & 31, ty = threadIdx.x >> 5;  // 32 x 8
#pragma unroll
  for (int r = ty; r < 32; r += 8) tile[r][tx] = in[(long)(k0 + r) * N + n0 + tx];
  __syncthreads();
#pragma unroll
  for (int r = ty; r < 32; r += 8) out[(long)(n0 + r) * K + k0 + tx] = f2bf(tile[tx][r]);
}

// ---------------- QKV GEMM: C = A[M][K] * Bt[N][K]^T + bias; scatter to Q,K,Vt ----------------
__global__ __launch_bounds__(256) void k_gemm_qkv(const u16* __restrict__ A,
                                                  const u16* __restrict__ Bt,
                                                  const float* __restrict__ bias,
                                                  u16* __restrict__ Qb, u16* __restrict__ Kb,
                                                  u16* __restrict__ Vt) {
  constexpr int K = DM;
  __shared__ u16 As[128 * 32], Bs[128 * 32];
  int m0 = blockIdx.y * 128, n0 = blockIdx.x * 128;
  int t = threadIdx.x, lane = t & 63, w = t >> 6;
  int l15 = lane & 15, lhi = lane >> 4;
  int wr = (w >> 1) * 64, wc = (w & 1) * 64;
  int srow = t >> 2, sk = (t & 3) * 8;
  const u16* Ap0 = A + (long)(m0 + srow) * K + sk;
  const u16* Ap1 = A + (long)(m0 + 64 + srow) * K + sk;
  const u16* Bp0 = Bt + (long)(n0 + srow) * K + sk;
  const u16* Bp1 = Bt + (long)(n0 + 64 + srow) * K + sk;
  u16* As0 = As + srow * 32 + sk; u16* As1 = As0 + 64 * 32;
  u16* Bs0 = Bs + srow * 32 + sk; u16* Bs1 = Bs0 + 64 * 32;

  f32x4 acc[4][4] = {};
  for (int k0 = 0; k0 < K; k0 += 32) {
    bf16x8 a0 = *(const bf16x8*)(Ap0 + k0);
    bf16x8 a1 = *(const bf16x8*)(Ap1 + k0);
    bf16x8 b0 = *(const bf16x8*)(Bp0 + k0);
    bf16x8 b1 = *(const bf16x8*)(Bp1 + k0);
    __syncthreads();
    *(bf16x8*)As0 = a0; *(bf16x8*)As1 = a1;
    *(bf16x8*)Bs0 = b0; *(bf16x8*)Bs1 = b1;
    __syncthreads();
    bf16x8 af[4], bg[4];
#pragma unroll
    for (int i = 0; i < 4; i++) af[i] = *(const bf16x8*)(As + (wr + i * 16 + l15) * 32 + lhi * 8);
#pragma unroll
    for (int j = 0; j < 4; j++) bg[j] = *(const bf16x8*)(Bs + (wc + j * 16 + l15) * 32 + lhi * 8);
#pragma unroll
    for (int i = 0; i < 4; i++)
#pragma unroll
      for (int j = 0; j < 4; j++)
        acc[i][j] = __builtin_amdgcn_mfma_f32_16x16x32_bf16(af[i], bg[j], acc[i][j], 0, 0, 0);
  }
#pragma unroll
  for (int i = 0; i < 4; i++)
#pragma unroll
    for (int j = 0; j < 4; j++) {
      int col = n0 + wc + j * 16 + l15;
      float bv = bias[col];
      int sec = col >> 11, dn = col & 2047, h = dn >> 7, hd = dn & 127;
#pragma unroll
      for (int r = 0; r < 4; r++) {
        int row = m0 + wr + i * 16 + lhi * 4 + r;
        int bb = row >> 11, ss = row & 2047;
        u16 val = f2bf(acc[i][j][r] + bv);
        if (sec == 0)
          Qb[(((long)(bb * NH + h)) * SEQ + ss) * HD + hd] = val;
        else if (sec == 1)
          Kb[(((long)(bb * NH + h)) * SEQ + ss) * HD + hd] = val;
        else
          Vt[(((long)(bb * NH + h)) * HD + hd) * SEQ + ss] = val;
      }
    }
}

// ---------------- output GEMM: out = A[M][K] * Bt[N][K]^T + bias (f32 out) ----------------
__global__ __launch_bounds__(256) void k_gemm_out(const u16* __restrict__ A,
                                                  const u16* __restrict__ Bt,
                                                  const float* __restrict__ bias,
                                                  float* __restrict__ Out) {
  constexpr int K = DM, N = DM;
  __shared__ u16 As[128 * 32], Bs[128 * 32];
  int m0 = blockIdx.y * 128, n0 = blockIdx.x * 128;
  int t = threadIdx.x, lane = t & 63, w = t >> 6;
  int l15 = lane & 15, lhi = lane >> 4;
  int wr = (w >> 1) * 64, wc = (w & 1) * 64;
  int srow = t >> 2, sk = (t & 3) * 8;
  const u16* Ap0 = A + (long)(m0 + srow) * K + sk;
  const u16* Ap1 = A + (long)(m0 + 64 + srow) * K + sk;
  const u16* Bp0 = Bt + (long)(n0 + srow) * K + sk;
  const u16* Bp1 = Bt + (long)(n0 + 64 + srow) * K + sk;
  u16* As0 = As + srow * 32 + sk; u16* As1 = As0 + 64 * 32;
  u16* Bs0 = Bs + srow * 32 + sk; u16* Bs1 = Bs0 + 64 * 32;

  f32x4 acc[4][4] = {};
  for (int k0 = 0; k0 < K; k0 += 32) {
    bf16x8 a0 = *(const bf16x8*)(Ap0 + k0);
    bf16x8 a1 = *(const bf16x8*)(Ap1 + k0);
    bf16x8 b0 = *(const bf16x8*)(Bp0 + k0);
    bf16x8 b1 = *(const bf16x8*)(Bp1 + k0);
    __syncthreads();
    *(bf16x8*)As0 = a0; *(bf16x8*)As1 = a1;
    *(bf16x8*)Bs0 = b0; *(bf16x8*)Bs1 = b1;
    __syncthreads();
    bf16x8 af[4], bg[4];
#pragma unroll
    for (int i = 0; i < 4; i++) af[i] = *(const bf16x8*)(As + (wr + i * 16 + l15) * 32 + lhi * 8);
#pragma unroll
    for (int j = 0; j < 4; j++) bg[j] = *(const bf16x8*)(Bs + (wc + j * 16 + l15) * 32 + lhi * 8);
#pragma unroll
    for (int i = 0; i < 4; i++)
#pragma unroll
      for (int j = 0; j < 4; j++)
        acc[i][j] = __builtin_amdgcn_mfma_f32_16x16x32_bf16(af[i], bg[j], acc[i][j], 0, 0, 0);
  }
#pragma unroll
  for (int i = 0; i < 4; i++)
#pragma unroll
    for (int j = 0; j < 4; j++) {
      int col = n0 + wc + j * 16 + l15;
      float bv = bias[col];
#pragma unroll
      for (int r = 0; r < 4; r++) {
        int row = m0 + wr + i * 16 + lhi * 4 + r;
        Out[(long)row * N + col] = acc[i][j][r] + bv;
      }
    }
}

// ---------------- flash attention (causal + alibi) ----------------
// Block-cooperative: K/V tiles double-buffered in LDS (XOR-swizzled), reg-staged with
// loads for tile kt+1 issued before computing tile kt (latency hidden under compute).
// Qb,Kb: [B*H][S][HD] bf16; Vt: [B*H][HD][S] bf16; mask: [H][S] f32; Ao: [B*S][DM] bf16
__global__ __launch_bounds__(256) void k_attn(const u16* __restrict__ Qb,
                                              const u16* __restrict__ Kb,
                                              const u16* __restrict__ Vt,
                                              const float* __restrict__ mask,
                                              u16* __restrict__ Ao) {
  int bh = blockIdx.y;                       // b*NH + h
  int qt = (gridDim.x - 1) - blockIdx.x;     // longest blocks first
  int t = threadIdx.x, w = t >> 6, lane = t & 63;
  int l15 = lane & 15, lhi = lane >> 4;
  int q0 = qt * 64 + w * 16;
  int b = bh >> 4, h = bh & 15;
  const u16* Qh = Qb + (long)bh * SEQ * HD;
  const u16* Kh = Kb + (long)bh * SEQ * HD;
  const u16* Vh = Vt + (long)bh * HD * SEQ;
  const float* mh = mask + h * SEQ;

  // LDS: K [64][128] x2, V [128][64] x2, both elem-swizzled (^ (row&7)<<3), + per-wave P
  __shared__ u16 Ks[2][64 * 128];
  __shared__ u16 Vs[2][128 * 64];
  __shared__ u16 p_lds[4 * 16 * 64];
  u16* pw = p_lds + w * (16 * 64);

  // staging geometry: 256 threads x 4 chunks of 8 elems (16B) per 16KB tile
  int krow[4], kcol[4], vrow[4], vcol[4];
#pragma unroll
  for (int i = 0; i < 4; i++) {
    int c = i * 256 + t;
    krow[i] = c >> 4; kcol[i] = (c & 15) * 8;   // K: 64 rows x 128 elems
    vrow[i] = c >> 3; vcol[i] = (c & 7) * 8;    // V: 128 rows x 64 elems
  }

  bf16x8 qf[4];
#pragma unroll
  for (int kc = 0; kc < 4; kc++)
    qf[kc] = *(const bf16x8*)(Qh + (long)(q0 + l15) * HD + kc * 32 + lhi * 8);

  int rowr[4];
#pragma unroll
  for (int r = 0; r < 4; r++) rowr[r] = q0 + lhi * 4 + r;

  float mrun[4], lrun[4];
  f32x4 oacc[8] = {};
#pragma unroll
  for (int r = 0; r < 4; r++) { mrun[r] = -1e30f; lrun[r] = 0.f; }

  const float sm_scale = 0.08838834764831845f;  // 1/sqrt(128)
  int nt = qt + 1;

  // prologue: stage tile 0 into buffer 0
  bf16x8 kst[4], vst[4];
#pragma unroll
  for (int i = 0; i < 4; i++) kst[i] = *(const bf16x8*)(Kh + (long)krow[i] * HD + kcol[i]);
#pragma unroll
  for (int i = 0; i < 4; i++) vst[i] = *(const bf16x8*)(Vh + (long)vrow[i] * SEQ + vcol[i]);
#pragma unroll
  for (int i = 0; i < 4; i++)
    *(bf16x8*)(Ks[0] + krow[i] * 128 + (kcol[i] ^ ((krow[i] & 7) << 3))) = kst[i];
#pragma unroll
  for (int i = 0; i < 4; i++)
    *(bf16x8*)(Vs[0] + vrow[i] * 64 + (vcol[i] ^ ((vrow[i] & 7) << 3))) = vst[i];
  __syncthreads();

  for (int kt = 0; kt < nt; kt++) {
    int kb = kt * 64;
    int cur = kt & 1, nxt = cur ^ 1;
    bool have_next = (kt + 1 < nt);
    bool diag = (kt == nt - 1);
    // ---- issue global loads for tile kt+1 (latency hides under this tile's compute) ----
    if (have_next) {
      int kb2 = kb + 64;
#pragma unroll
      for (int i = 0; i < 4; i++)
        kst[i] = *(const bf16x8*)(Kh + (long)(kb2 + krow[i]) * HD + kcol[i]);
#pragma unroll
      for (int i = 0; i < 4; i++)
        vst[i] = *(const bf16x8*)(Vh + (long)vrow[i] * SEQ + kb2 + vcol[i]);
    }
    // ---- alibi bias for this tile ----
    float bvv[4];
#pragma unroll
    for (int cb = 0; cb < 4; cb++) bvv[cb] = mh[kb + cb * 16 + l15];
    // ---- QK^T from LDS ----
    const u16* Kc = Ks[cur];
    f32x4 sc[4] = {};
#pragma unroll
    for (int kc = 0; kc < 4; kc++)
#pragma unroll
      for (int cb = 0; cb < 4; cb++) {
        int rr = cb * 16 + l15;
        bf16x8 kf = *(const bf16x8*)(Kc + rr * 128 + ((kc * 32 + lhi * 8) ^ ((rr & 7) << 3)));
        sc[cb] = __builtin_amdgcn_mfma_f32_16x16x32_bf16(qf[kc], kf, sc[cb], 0, 0, 0);
      }
    // ---- alibi + causal + running softmax ----
    float p[4][4], tmax[4];
#pragma unroll
    for (int r = 0; r < 4; r++) tmax[r] = -1e30f;
#pragma unroll
    for (int cb = 0; cb < 4; cb++) {
      int col = kb + cb * 16 + l15;
#pragma unroll
      for (int r = 0; r < 4; r++) {
        float v = sc[cb][r] * sm_scale + bvv[cb];
        if (diag) v = (col <= rowr[r]) ? v : -1e30f;
        p[cb][r] = v;
        tmax[r] = fmaxf(tmax[r], v);
      }
    }
    float alpha[4];
#pragma unroll
    for (int r = 0; r < 4; r++) {
      float v = tmax[r];
      v = fmaxf(v, __shfl_xor(v, 1));
      v = fmaxf(v, __shfl_xor(v, 2));
      v = fmaxf(v, __shfl_xor(v, 4));
      v = fmaxf(v, __shfl_xor(v, 8));
      float mnew = fmaxf(mrun[r], v);
      alpha[r] = __expf(mrun[r] - mnew);
      mrun[r] = mnew;
      float s = 0.f;
#pragma unroll
      for (int cb = 0; cb < 4; cb++) {
        float e = __expf(p[cb][r] - mnew);
        p[cb][r] = e;
        s += e;
      }
      s += __shfl_xor(s, 1); s += __shfl_xor(s, 2);
      s += __shfl_xor(s, 4); s += __shfl_xor(s, 8);
      lrun[r] = lrun[r] * alpha[r] + s;
    }
#pragma unroll
    for (int nb = 0; nb < 8; nb++)
#pragma unroll
      for (int r = 0; r < 4; r++) oacc[nb][r] *= alpha[r];
    // ---- P -> per-wave LDS (swizzled), wave-local ----
#pragma unroll
    for (int cb = 0; cb < 4; cb++)
#pragma unroll
      for (int r = 0; r < 4; r++) {
        int rr = lhi * 4 + r;
        pw[(rr * 64 + cb * 16 + l15) ^ ((rr & 7) << 3)] = f2bf(p[cb][r]);
      }
    asm volatile("s_waitcnt lgkmcnt(0)" ::: "memory");
    bf16x8 pa0 = *(const bf16x8*)(pw + ((l15 * 64 + lhi * 8) ^ ((l15 & 7) << 3)));
    bf16x8 pa1 = *(const bf16x8*)(pw + ((l15 * 64 + 32 + lhi * 8) ^ ((l15 & 7) << 3)));
    // ---- PV from LDS ----
    const u16* Vc = Vs[cur];
#pragma unroll
    for (int nb = 0; nb < 8; nb++) {
      int rr = nb * 16 + l15;
      bf16x8 vf0 = *(const bf16x8*)(Vc + rr * 64 + ((lhi * 8) ^ ((rr & 7) << 3)));
      bf16x8 vf1 = *(const bf16x8*)(Vc + rr * 64 + ((32 + lhi * 8) ^ ((rr & 7) << 3)));
      oacc[nb] = __builtin_amdgcn_mfma_f32_16x16x32_bf16(pa0, vf0, oacc[nb], 0, 0, 0);
      oacc[nb] = __builtin_amdgcn_mfma_f32_16x16x32_bf16(pa1, vf1, oacc[nb], 0, 0, 0);
    }
    // ---- write staged regs into the other buffer, then one barrier ----
    if (have_next) {
#pragma unroll
      for (int i = 0; i < 4; i++)
        *(bf16x8*)(Ks[nxt] + krow[i] * 128 + (kcol[i] ^ ((krow[i] & 7) << 3))) = kst[i];
#pragma unroll
      for (int i = 0; i < 4; i++)
        *(bf16x8*)(Vs[nxt] + vrow[i] * 64 + (vcol[i] ^ ((vrow[i] & 7) << 3))) = vst[i];
    }
    __syncthreads();
  }
#pragma unroll
  for (int nb = 0; nb < 8; nb++)
#pragma unroll
    for (int r = 0; r < 4; r++) {
      int row = q0 + lhi * 4 + r;
      float v = oacc[nb][r] / lrun[r];
      Ao[((long)(b * SEQ + row)) * DM + h * HD + nb * 16 + l15] = f2bf(v);
    }
}

// ---------------- launcher ----------------
extern "C" void kernel_launch(void* const* d_in, const int* in_sizes, int n_in,
                              void* d_out, int out_size, void* d_ws, size_t ws_size,
                              hipStream_t stream) {
  const float* x    = (const float*)d_in[0];
  const float* amsk = (const float*)d_in[1];
  const float* Wqkv = (const float*)d_in[2];
  const float* bqkv = (const float*)d_in[3];
  const float* Wout = (const float*)d_in[4];
  const float* bout = (const float*)d_in[5];
  float* out = (float*)d_out;

  // workspace layout (bf16 buffers), total ~112 MB
  char* ws = (char*)d_ws;
  u16* xb  = (u16*)(ws + 0);                   // [4096][2048]
  u16* WqT = (u16*)(ws + 16777216UL);          // [6144][2048]
  u16* WoT = (u16*)(ws + 41943040UL);          // [2048][2048]
  u16* Qb  = (u16*)(ws + 50331648UL);          // [B*H][S][HD]
  u16* Kb  = (u16*)(ws + 67108864UL);          // [B*H][S][HD]
  u16* Vt  = (u16*)(ws + 83886080UL);          // [B*H][HD][S]
  u16* Ao  = (u16*)(ws + 100663296UL);         // [4096][2048]

  k_cvt<<<8192, 256, 0, stream>>>(x, xb, (MROWS * DM) / 4);
  k_transpose<<<dim3(N3 / 32, DM / 32), 256, 0, stream>>>(Wqkv, WqT, DM, N3);
  k_transpose<<<dim3(DM / 32, DM / 32), 256, 0, stream>>>(Wout, WoT, DM, DM);
  k_gemm_qkv<<<dim3(N3 / 128, MROWS / 128), 256, 0, stream>>>(xb, WqT, bqkv, Qb, Kb, Vt);
  k_attn<<<dim3(SEQ / 64, BATCH * NH), 256, 0, stream>>>(Qb, Kb, Vt, amsk, Ao);
  k_gemm_out<<<dim3(DM / 128, MROWS / 128), 256, 0, stream>>>(Ao, WoT, bout, out);
}

// Round 4
// 382.995 us; speedup vs baseline: 2.2801x; 1.0548x over previous
//
#include <hip/hip_runtime.h>
#include <hip/hip_bf16.h>

typedef __bf16 bf16x8 __attribute__((ext_vector_type(8)));
typedef float f32x4 __attribute__((ext_vector_type(4)));
typedef unsigned short u16;

constexpr int BATCH = 2, SEQ = 2048, DM = 2048, NH = 16, HD = 128;
constexpr int N3 = 3 * DM;          // 6144
constexpr int MROWS = BATCH * SEQ;  // 4096

__device__ __forceinline__ u16 f2bf(float f) {
  unsigned u = __builtin_bit_cast(unsigned, f);
  unsigned r = 0x7FFFu + ((u >> 16) & 1u);
  return (u16)((u + r) >> 16);
}

// async global->LDS, 16B per lane; LDS dest = wave-uniform base + lane*16
__device__ __forceinline__ void glds16(const u16* g, u16* l) {
  __builtin_amdgcn_global_load_lds(
      (const __attribute__((address_space(1))) unsigned*)(const void*)g,
      (__attribute__((address_space(3))) unsigned*)(void*)l, 16, 0, 0);
}

// ---------------- convert f32 -> bf16 (n4 = n/4 float4 groups) ----------------
__global__ __launch_bounds__(256) void k_cvt(const float* __restrict__ in,
                                             u16* __restrict__ out, int n4) {
  int i = blockIdx.x * blockDim.x + threadIdx.x;
  if (i >= n4) return;
  float4 v = reinterpret_cast<const float4*>(in)[i];
  ushort4 o;
  o.x = f2bf(v.x); o.y = f2bf(v.y); o.z = f2bf(v.z); o.w = f2bf(v.w);
  reinterpret_cast<ushort4*>(out)[i] = o;
}

// ---------------- transpose f32 [K][N] -> bf16 [N][K] ----------------
__global__ __launch_bounds__(256) void k_transpose(const float* __restrict__ in,
                                                   u16* __restrict__ out, int K, int N) {
  __shared__ float tile[32][33];
  int n0 = blockIdx.x * 32, k0 = blockIdx.y * 32;
  int tx = threadIdx.x & 31, ty = threadIdx.x >> 5;  // 32 x 8
#pragma unroll
  for (int r = ty; r < 32; r += 8) tile[r][tx] = in[(long)(k0 + r) * N + n0 + tx];
  __syncthreads();
#pragma unroll
  for (int r = ty; r < 32; r += 8) out[(long)(n0 + r) * K + k0 + tx] = f2bf(tile[tx][r]);
}

// ---------------- QKV GEMM (m97 structure): C = A * Bt^T + bias; scatter to Q,K,Vt ----------------
__global__ __launch_bounds__(256) void k_gemm_qkv(const u16* __restrict__ A,
                                                  const u16* __restrict__ Bt,
                                                  const float* __restrict__ bias,
                                                  u16* __restrict__ Qb, u16* __restrict__ Kb,
                                                  u16* __restrict__ Vt) {
  constexpr int K = DM;
  __shared__ u16 As[128 * 32], Bs[128 * 32];
  int m0 = blockIdx.y * 128, n0 = blockIdx.x * 128;
  int t = threadIdx.x, lane = t & 63, w = t >> 6;
  int l15 = lane & 15, lhi = lane >> 4;
  int wr = (w >> 1) * 64, wc = (w & 1) * 64;
  int srow = t >> 2, sk = (t & 3) * 8;
  const u16* Ap0 = A + (long)(m0 + srow) * K + sk;
  const u16* Ap1 = A + (long)(m0 + 64 + srow) * K + sk;
  const u16* Bp0 = Bt + (long)(n0 + srow) * K + sk;
  const u16* Bp1 = Bt + (long)(n0 + 64 + srow) * K + sk;
  // wave-uniform LDS staging bases (chunk id == t; elem offset t*8)
  u16* AsW0 = As + w * 512; u16* AsW1 = As + 2048 + w * 512;
  u16* BsW0 = Bs + w * 512; u16* BsW1 = Bs + 2048 + w * 512;

  f32x4 acc[4][4] = {};
  for (int k0 = 0; k0 < K; k0 += 32) {
    glds16(Ap0 + k0, AsW0);
    glds16(Ap1 + k0, AsW1);
    glds16(Bp0 + k0, BsW0);
    glds16(Bp1 + k0, BsW1);
    __syncthreads();  // drains vmcnt (loads landed) for all waves
    bf16x8 af[4], bg[4];
#pragma unroll
    for (int i = 0; i < 4; i++) af[i] = *(const bf16x8*)(As + (wr + i * 16 + l15) * 32 + lhi * 8);
#pragma unroll
    for (int j = 0; j < 4; j++) bg[j] = *(const bf16x8*)(Bs + (wc + j * 16 + l15) * 32 + lhi * 8);
#pragma unroll
    for (int i = 0; i < 4; i++)
#pragma unroll
      for (int j = 0; j < 4; j++)
        acc[i][j] = __builtin_amdgcn_mfma_f32_16x16x32_bf16(af[i], bg[j], acc[i][j], 0, 0, 0);
    __syncthreads();  // all frag reads done before next overwrite
  }
#pragma unroll
  for (int i = 0; i < 4; i++)
#pragma unroll
    for (int j = 0; j < 4; j++) {
      int col = n0 + wc + j * 16 + l15;
      float bv = bias[col];
      int sec = col >> 11, dn = col & 2047, h = dn >> 7, hd = dn & 127;
#pragma unroll
      for (int r = 0; r < 4; r++) {
        int row = m0 + wr + i * 16 + lhi * 4 + r;
        int bb = row >> 11, ss = row & 2047;
        u16 val = f2bf(acc[i][j][r] + bv);
        if (sec == 0)
          Qb[(((long)(bb * NH + h)) * SEQ + ss) * HD + hd] = val;
        else if (sec == 1)
          Kb[(((long)(bb * NH + h)) * SEQ + ss) * HD + hd] = val;
        else
          Vt[(((long)(bb * NH + h)) * HD + hd) * SEQ + ss] = val;
      }
    }
}

// ---------------- output GEMM (m97 structure): out = A * Bt^T + bias (f32 out) ----------------
__global__ __launch_bounds__(256) void k_gemm_out(const u16* __restrict__ A,
                                                  const u16* __restrict__ Bt,
                                                  const float* __restrict__ bias,
                                                  float* __restrict__ Out) {
  constexpr int K = DM, N = DM;
  __shared__ u16 As[128 * 32], Bs[128 * 32];
  int m0 = blockIdx.y * 128, n0 = blockIdx.x * 128;
  int t = threadIdx.x, lane = t & 63, w = t >> 6;
  int l15 = lane & 15, lhi = lane >> 4;
  int wr = (w >> 1) * 64, wc = (w & 1) * 64;
  int srow = t >> 2, sk = (t & 3) * 8;
  const u16* Ap0 = A + (long)(m0 + srow) * K + sk;
  const u16* Ap1 = A + (long)(m0 + 64 + srow) * K + sk;
  const u16* Bp0 = Bt + (long)(n0 + srow) * K + sk;
  const u16* Bp1 = Bt + (long)(n0 + 64 + srow) * K + sk;
  u16* AsW0 = As + w * 512; u16* AsW1 = As + 2048 + w * 512;
  u16* BsW0 = Bs + w * 512; u16* BsW1 = Bs + 2048 + w * 512;

  f32x4 acc[4][4] = {};
  for (int k0 = 0; k0 < K; k0 += 32) {
    glds16(Ap0 + k0, AsW0);
    glds16(Ap1 + k0, AsW1);
    glds16(Bp0 + k0, BsW0);
    glds16(Bp1 + k0, BsW1);
    __syncthreads();
    bf16x8 af[4], bg[4];
#pragma unroll
    for (int i = 0; i < 4; i++) af[i] = *(const bf16x8*)(As + (wr + i * 16 + l15) * 32 + lhi * 8);
#pragma unroll
    for (int j = 0; j < 4; j++) bg[j] = *(const bf16x8*)(Bs + (wc + j * 16 + l15) * 32 + lhi * 8);
#pragma unroll
    for (int i = 0; i < 4; i++)
#pragma unroll
      for (int j = 0; j < 4; j++)
        acc[i][j] = __builtin_amdgcn_mfma_f32_16x16x32_bf16(af[i], bg[j], acc[i][j], 0, 0, 0);
    __syncthreads();
  }
#pragma unroll
  for (int i = 0; i < 4; i++)
#pragma unroll
    for (int j = 0; j < 4; j++) {
      int col = n0 + wc + j * 16 + l15;
      float bv = bias[col];
#pragma unroll
      for (int r = 0; r < 4; r++) {
        int row = m0 + wr + i * 16 + lhi * 4 + r;
        Out[(long)row * N + col] = acc[i][j][r] + bv;
      }
    }
}

// ---------------- flash attention (causal + alibi) ----------------
// Single-buffered K/V in LDS (40KB total -> 4 blocks/CU), reg-prefetch of tile kt+1
// issued before computing tile kt; two barriers per tile.
__global__ __launch_bounds__(256) void k_attn(const u16* __restrict__ Qb,
                                              const u16* __restrict__ Kb,
                                              const u16* __restrict__ Vt,
                                              const float* __restrict__ mask,
                                              u16* __restrict__ Ao) {
  int bh = blockIdx.y;                       // b*NH + h
  int qt = (gridDim.x - 1) - blockIdx.x;     // longest blocks first
  int t = threadIdx.x, w = t >> 6, lane = t & 63;
  int l15 = lane & 15, lhi = lane >> 4;
  int q0 = qt * 64 + w * 16;
  int b = bh >> 4, h = bh & 15;
  const u16* Qh = Qb + (long)bh * SEQ * HD;
  const u16* Kh = Kb + (long)bh * SEQ * HD;
  const u16* Vh = Vt + (long)bh * HD * SEQ;
  const float* mh = mask + h * SEQ;

  // LDS: K [64][128], V [128][64], elem-swizzled (^ (row&7)<<3), + per-wave P
  __shared__ u16 Ks[64 * 128];
  __shared__ u16 Vs[128 * 64];
  __shared__ u16 p_lds[4 * 16 * 64];
  u16* pw = p_lds + w * (16 * 64);

  int krow[4], kcol[4], vrow[4], vcol[4];
#pragma unroll
  for (int i = 0; i < 4; i++) {
    int c = i * 256 + t;
    krow[i] = c >> 4; kcol[i] = (c & 15) * 8;   // K: 64 rows x 128 elems
    vrow[i] = c >> 3; vcol[i] = (c & 7) * 8;    // V: 128 rows x 64 elems
  }

  bf16x8 qf[4];
#pragma unroll
  for (int kc = 0; kc < 4; kc++)
    qf[kc] = *(const bf16x8*)(Qh + (long)(q0 + l15) * HD + kc * 32 + lhi * 8);

  int rowr[4];
#pragma unroll
  for (int r = 0; r < 4; r++) rowr[r] = q0 + lhi * 4 + r;

  float mrun[4], lrun[4];
  f32x4 oacc[8] = {};
#pragma unroll
  for (int r = 0; r < 4; r++) { mrun[r] = -1e30f; lrun[r] = 0.f; }

  const float sm_scale = 0.08838834764831845f;  // 1/sqrt(128)
  int nt = qt + 1;

  // prologue: stage tile 0
  bf16x8 kst[4], vst[4];
#pragma unroll
  for (int i = 0; i < 4; i++) kst[i] = *(const bf16x8*)(Kh + (long)krow[i] * HD + kcol[i]);
#pragma unroll
  for (int i = 0; i < 4; i++) vst[i] = *(const bf16x8*)(Vh + (long)vrow[i] * SEQ + vcol[i]);
#pragma unroll
  for (int i = 0; i < 4; i++)
    *(bf16x8*)(Ks + krow[i] * 128 + (kcol[i] ^ ((krow[i] & 7) << 3))) = kst[i];
#pragma unroll
  for (int i = 0; i < 4; i++)
    *(bf16x8*)(Vs + vrow[i] * 64 + (vcol[i] ^ ((vrow[i] & 7) << 3))) = vst[i];
  __syncthreads();

  for (int kt = 0; kt < nt; kt++) {
    int kb = kt * 64;
    bool have_next = (kt + 1 < nt);
    bool diag = (kt == nt - 1);
    // ---- issue global loads for tile kt+1 (hide HBM latency under compute) ----
    if (have_next) {
      int kb2 = kb + 64;
#pragma unroll
      for (int i = 0; i < 4; i++)
        kst[i] = *(const bf16x8*)(Kh + (long)(kb2 + krow[i]) * HD + kcol[i]);
#pragma unroll
      for (int i = 0; i < 4; i++)
        vst[i] = *(const bf16x8*)(Vh + (long)vrow[i] * SEQ + kb2 + vcol[i]);
    }
    float bvv[4];
#pragma unroll
    for (int cb = 0; cb < 4; cb++) bvv[cb] = mh[kb + cb * 16 + l15];
    // ---- QK^T from LDS ----
    f32x4 sc[4] = {};
    __builtin_amdgcn_s_setprio(1);
#pragma unroll
    for (int kc = 0; kc < 4; kc++)
#pragma unroll
      for (int cb = 0; cb < 4; cb++) {
        int rr = cb * 16 + l15;
        bf16x8 kf = *(const bf16x8*)(Ks + rr * 128 + ((kc * 32 + lhi * 8) ^ ((rr & 7) << 3)));
        sc[cb] = __builtin_amdgcn_mfma_f32_16x16x32_bf16(qf[kc], kf, sc[cb], 0, 0, 0);
      }
    __builtin_amdgcn_s_setprio(0);
    // ---- alibi + causal + running softmax ----
    float p[4][4], tmax[4];
#pragma unroll
    for (int cb = 0; cb < 4; cb++) {
      int col = kb + cb * 16 + l15;
#pragma unroll
      for (int r = 0; r < 4; r++) {
        float v = sc[cb][r] * sm_scale + bvv[cb];
        if (diag) v = (col <= rowr[r]) ? v : -1e30f;
        p[cb][r] = v;
      }
    }
#pragma unroll
    for (int r = 0; r < 4; r++)
      tmax[r] = fmaxf(fmaxf(p[0][r], p[1][r]), fmaxf(p[2][r], p[3][r]));
    float alpha[4];
#pragma unroll
    for (int r = 0; r < 4; r++) {
      float v = tmax[r];
      v = fmaxf(v, __shfl_xor(v, 1));
      v = fmaxf(v, __shfl_xor(v, 2));
      v = fmaxf(v, __shfl_xor(v, 4));
      v = fmaxf(v, __shfl_xor(v, 8));
      float mnew = fmaxf(mrun[r], v);
      alpha[r] = __expf(mrun[r] - mnew);
      mrun[r] = mnew;
      float s = 0.f;
#pragma unroll
      for (int cb = 0; cb < 4; cb++) {
        float e = __expf(p[cb][r] - mnew);
        p[cb][r] = e;
        s += e;
      }
      s += __shfl_xor(s, 1); s += __shfl_xor(s, 2);
      s += __shfl_xor(s, 4); s += __shfl_xor(s, 8);
      lrun[r] = lrun[r] * alpha[r] + s;
    }
#pragma unroll
    for (int nb = 0; nb < 8; nb++)
#pragma unroll
      for (int r = 0; r < 4; r++) oacc[nb][r] *= alpha[r];
    // ---- P -> per-wave LDS (swizzled), wave-local ----
#pragma unroll
    for (int cb = 0; cb < 4; cb++)
#pragma unroll
      for (int r = 0; r < 4; r++) {
        int rr = lhi * 4 + r;
        pw[(rr * 64 + cb * 16 + l15) ^ ((rr & 7) << 3)] = f2bf(p[cb][r]);
      }
    asm volatile("s_waitcnt lgkmcnt(0)" ::: "memory");
    bf16x8 pa0 = *(const bf16x8*)(pw + ((l15 * 64 + lhi * 8) ^ ((l15 & 7) << 3)));
    bf16x8 pa1 = *(const bf16x8*)(pw + ((l15 * 64 + 32 + lhi * 8) ^ ((l15 & 7) << 3)));
    // ---- PV from LDS ----
    __builtin_amdgcn_s_setprio(1);
#pragma unroll
    for (int nb = 0; nb < 8; nb++) {
      int rr = nb * 16 + l15;
      bf16x8 vf0 = *(const bf16x8*)(Vs + rr * 64 + ((lhi * 8) ^ ((rr & 7) << 3)));
      bf16x8 vf1 = *(const bf16x8*)(Vs + rr * 64 + ((32 + lhi * 8) ^ ((rr & 7) << 3)));
      oacc[nb] = __builtin_amdgcn_mfma_f32_16x16x32_bf16(pa0, vf0, oacc[nb], 0, 0, 0);
      oacc[nb] = __builtin_amdgcn_mfma_f32_16x16x32_bf16(pa1, vf1, oacc[nb], 0, 0, 0);
    }
    __builtin_amdgcn_s_setprio(0);
    // ---- single-buffer swap: all reads done -> write staged regs -> visible ----
    if (have_next) {
      __syncthreads();
#pragma unroll
      for (int i = 0; i < 4; i++)
        *(bf16x8*)(Ks + krow[i] * 128 + (kcol[i] ^ ((krow[i] & 7) << 3))) = kst[i];
#pragma unroll
      for (int i = 0; i < 4; i++)
        *(bf16x8*)(Vs + vrow[i] * 64 + (vcol[i] ^ ((vrow[i] & 7) << 3))) = vst[i];
      __syncthreads();
    }
  }
#pragma unroll
  for (int nb = 0; nb < 8; nb++)
#pragma unroll
    for (int r = 0; r < 4; r++) {
      int row = q0 + lhi * 4 + r;
      float v = oacc[nb][r] / lrun[r];
      Ao[((long)(b * SEQ + row)) * DM + h * HD + nb * 16 + l15] = f2bf(v);
    }
}

// ---------------- launcher ----------------
extern "C" void kernel_launch(void* const* d_in, const int* in_sizes, int n_in,
                              void* d_out, int out_size, void* d_ws, size_t ws_size,
                              hipStream_t stream) {
  const float* x    = (const float*)d_in[0];
  const float* amsk = (const float*)d_in[1];
  const float* Wqkv = (const float*)d_in[2];
  const float* bqkv = (const float*)d_in[3];
  const float* Wout = (const float*)d_in[4];
  const float* bout = (const float*)d_in[5];
  float* out = (float*)d_out;

  char* ws = (char*)d_ws;
  u16* xb  = (u16*)(ws + 0);                   // [4096][2048]
  u16* WqT = (u16*)(ws + 16777216UL);          // [6144][2048]
  u16* WoT = (u16*)(ws + 41943040UL);          // [2048][2048]
  u16* Qb  = (u16*)(ws + 50331648UL);          // [B*H][S][HD]
  u16* Kb  = (u16*)(ws + 67108864UL);          // [B*H][S][HD]
  u16* Vt  = (u16*)(ws + 83886080UL);          // [B*H][HD][S]
  u16* Ao  = (u16*)(ws + 100663296UL);         // [4096][2048]

  k_cvt<<<8192, 256, 0, stream>>>(x, xb, (MROWS * DM) / 4);
  k_transpose<<<dim3(N3 / 32, DM / 32), 256, 0, stream>>>(Wqkv, WqT, DM, N3);
  k_transpose<<<dim3(DM / 32, DM / 32), 256, 0, stream>>>(Wout, WoT, DM, DM);
  k_gemm_qkv<<<dim3(N3 / 128, MROWS / 128), 256, 0, stream>>>(xb, WqT, bqkv, Qb, Kb, Vt);
  k_attn<<<dim3(SEQ / 64, BATCH * NH), 256, 0, stream>>>(Qb, Kb, Vt, amsk, Ao);
  k_gemm_out<<<dim3(DM / 128, MROWS / 128), 256, 0, stream>>>(Ao, WoT, bout, out);
}

// Round 5
// 310.760 us; speedup vs baseline: 2.8101x; 1.2324x over previous
//
#include <hip/hip_runtime.h>
#include <hip/hip_bf16.h>

typedef __bf16 bf16x8 __attribute__((ext_vector_type(8)));
typedef float f32x4 __attribute__((ext_vector_type(4)));
typedef unsigned short u16;

constexpr int BATCH = 2, SEQ = 2048, DM = 2048, NH = 16, HD = 128;
constexpr int N3 = 3 * DM;          // 6144
constexpr int MROWS = BATCH * SEQ;  // 4096

__device__ __forceinline__ u16 f2bf(float f) {
  unsigned u = __builtin_bit_cast(unsigned, f);
  unsigned r = 0x7FFFu + ((u >> 16) & 1u);
  return (u16)((u + r) >> 16);
}

// async global->LDS, 16B per lane; LDS dest = wave-uniform base + lane*16
__device__ __forceinline__ void glds16(const u16* g, u16* l) {
  __builtin_amdgcn_global_load_lds(
      (const __attribute__((address_space(1))) unsigned*)(const void*)g,
      (__attribute__((address_space(3))) unsigned*)(void*)l, 16, 0, 0);
}

// ---------------- convert f32 -> bf16 (n4 = n/4 float4 groups) ----------------
__global__ __launch_bounds__(256) void k_cvt(const float* __restrict__ in,
                                             u16* __restrict__ out, int n4) {
  int i = blockIdx.x * blockDim.x + threadIdx.x;
  if (i >= n4) return;
  float4 v = reinterpret_cast<const float4*>(in)[i];
  ushort4 o;
  o.x = f2bf(v.x); o.y = f2bf(v.y); o.z = f2bf(v.z); o.w = f2bf(v.w);
  reinterpret_cast<ushort4*>(out)[i] = o;
}

// ---------------- transpose f32 [K][N] -> bf16 [N][K] ----------------
__global__ __launch_bounds__(256) void k_transpose(const float* __restrict__ in,
                                                   u16* __restrict__ out, int K, int N) {
  __shared__ float tile[32][33];
  int n0 = blockIdx.x * 32, k0 = blockIdx.y * 32;
  int tx = threadIdx.x & 31, ty = threadIdx.x >> 5;  // 32 x 8
#pragma unroll
  for (int r = ty; r < 32; r += 8) tile[r][tx] = in[(long)(k0 + r) * N + n0 + tx];
  __syncthreads();
#pragma unroll
  for (int r = ty; r < 32; r += 8) out[(long)(n0 + r) * K + k0 + tx] = f2bf(tile[tx][r]);
}

// ---------------- QKV GEMM (m97 structure): C = A * Bt^T + bias; scatter to Q,K,Vt ----------------
__global__ __launch_bounds__(256) void k_gemm_qkv(const u16* __restrict__ A,
                                                  const u16* __restrict__ Bt,
                                                  const float* __restrict__ bias,
                                                  u16* __restrict__ Qb, u16* __restrict__ Kb,
                                                  u16* __restrict__ Vt) {
  constexpr int K = DM;
  __shared__ u16 As[128 * 32], Bs[128 * 32];
  int m0 = blockIdx.y * 128, n0 = blockIdx.x * 128;
  int t = threadIdx.x, lane = t & 63, w = t >> 6;
  int l15 = lane & 15, lhi = lane >> 4;
  int wr = (w >> 1) * 64, wc = (w & 1) * 64;
  int srow = t >> 2, sk = (t & 3) * 8;
  const u16* Ap0 = A + (long)(m0 + srow) * K + sk;
  const u16* Ap1 = A + (long)(m0 + 64 + srow) * K + sk;
  const u16* Bp0 = Bt + (long)(n0 + srow) * K + sk;
  const u16* Bp1 = Bt + (long)(n0 + 64 + srow) * K + sk;
  // wave-uniform LDS staging bases (chunk id == t; elem offset t*8)
  u16* AsW0 = As + w * 512; u16* AsW1 = As + 2048 + w * 512;
  u16* BsW0 = Bs + w * 512; u16* BsW1 = Bs + 2048 + w * 512;

  f32x4 acc[4][4] = {};
  for (int k0 = 0; k0 < K; k0 += 32) {
    glds16(Ap0 + k0, AsW0);
    glds16(Ap1 + k0, AsW1);
    glds16(Bp0 + k0, BsW0);
    glds16(Bp1 + k0, BsW1);
    __syncthreads();  // drains vmcnt (loads landed) for all waves
    bf16x8 af[4], bg[4];
#pragma unroll
    for (int i = 0; i < 4; i++) af[i] = *(const bf16x8*)(As + (wr + i * 16 + l15) * 32 + lhi * 8);
#pragma unroll
    for (int j = 0; j < 4; j++) bg[j] = *(const bf16x8*)(Bs + (wc + j * 16 + l15) * 32 + lhi * 8);
#pragma unroll
    for (int i = 0; i < 4; i++)
#pragma unroll
      for (int j = 0; j < 4; j++)
        acc[i][j] = __builtin_amdgcn_mfma_f32_16x16x32_bf16(af[i], bg[j], acc[i][j], 0, 0, 0);
    __syncthreads();  // all frag reads done before next overwrite
  }
#pragma unroll
  for (int i = 0; i < 4; i++)
#pragma unroll
    for (int j = 0; j < 4; j++) {
      int col = n0 + wc + j * 16 + l15;
      float bv = bias[col];
      int sec = col >> 11, dn = col & 2047, h = dn >> 7, hd = dn & 127;
#pragma unroll
      for (int r = 0; r < 4; r++) {
        int row = m0 + wr + i * 16 + lhi * 4 + r;
        int bb = row >> 11, ss = row & 2047;
        u16 val = f2bf(acc[i][j][r] + bv);
        if (sec == 0)
          Qb[(((long)(bb * NH + h)) * SEQ + ss) * HD + hd] = val;
        else if (sec == 1)
          Kb[(((long)(bb * NH + h)) * SEQ + ss) * HD + hd] = val;
        else
          Vt[(((long)(bb * NH + h)) * HD + hd) * SEQ + ss] = val;
      }
    }
}

// ---------------- output GEMM (m97 structure): out = A * Bt^T + bias (f32 out) ----------------
__global__ __launch_bounds__(256) void k_gemm_out(const u16* __restrict__ A,
                                                  const u16* __restrict__ Bt,
                                                  const float* __restrict__ bias,
                                                  float* __restrict__ Out) {
  constexpr int K = DM, N = DM;
  __shared__ u16 As[128 * 32], Bs[128 * 32];
  int m0 = blockIdx.y * 128, n0 = blockIdx.x * 128;
  int t = threadIdx.x, lane = t & 63, w = t >> 6;
  int l15 = lane & 15, lhi = lane >> 4;
  int wr = (w >> 1) * 64, wc = (w & 1) * 64;
  int srow = t >> 2, sk = (t & 3) * 8;
  const u16* Ap0 = A + (long)(m0 + srow) * K + sk;
  const u16* Ap1 = A + (long)(m0 + 64 + srow) * K + sk;
  const u16* Bp0 = Bt + (long)(n0 + srow) * K + sk;
  const u16* Bp1 = Bt + (long)(n0 + 64 + srow) * K + sk;
  u16* AsW0 = As + w * 512; u16* AsW1 = As + 2048 + w * 512;
  u16* BsW0 = Bs + w * 512; u16* BsW1 = Bs + 2048 + w * 512;

  f32x4 acc[4][4] = {};
  for (int k0 = 0; k0 < K; k0 += 32) {
    glds16(Ap0 + k0, AsW0);
    glds16(Ap1 + k0, AsW1);
    glds16(Bp0 + k0, BsW0);
    glds16(Bp1 + k0, BsW1);
    __syncthreads();
    bf16x8 af[4], bg[4];
#pragma unroll
    for (int i = 0; i < 4; i++) af[i] = *(const bf16x8*)(As + (wr + i * 16 + l15) * 32 + lhi * 8);
#pragma unroll
    for (int j = 0; j < 4; j++) bg[j] = *(const bf16x8*)(Bs + (wc + j * 16 + l15) * 32 + lhi * 8);
#pragma unroll
    for (int i = 0; i < 4; i++)
#pragma unroll
      for (int j = 0; j < 4; j++)
        acc[i][j] = __builtin_amdgcn_mfma_f32_16x16x32_bf16(af[i], bg[j], acc[i][j], 0, 0, 0);
    __syncthreads();
  }
#pragma unroll
  for (int i = 0; i < 4; i++)
#pragma unroll
    for (int j = 0; j < 4; j++) {
      int col = n0 + wc + j * 16 + l15;
      float bv = bias[col];
#pragma unroll
      for (int r = 0; r < 4; r++) {
        int row = m0 + wr + i * 16 + lhi * 4 + r;
        Out[(long)row * N + col] = acc[i][j][r] + bv;
      }
    }
}

// ---------------- flash attention (causal + alibi), load-balanced ----------------
// Each block handles TWO complementary q-tiles (long first): qt = NT-1-x, then x.
// Every block = exactly NT+1 tile-iterations -> perfect CU balance.
// Single-buffered K/V in LDS, reg-prefetch of tile kt+1 during tile kt.
__global__ __launch_bounds__(256) void k_attn(const u16* __restrict__ Qb,
                                              const u16* __restrict__ Kb,
                                              const u16* __restrict__ Vt,
                                              const float* __restrict__ mask,
                                              u16* __restrict__ Ao) {
  constexpr int NT = SEQ / 64;  // 32
  int bh = blockIdx.y;          // b*NH + h
  int qp = blockIdx.x;          // 0..NT/2-1
  int t = threadIdx.x, w = t >> 6, lane = t & 63;
  int l15 = lane & 15, lhi = lane >> 4;
  int b = bh >> 4, h = bh & 15;
  const u16* Qh = Qb + (long)bh * SEQ * HD;
  const u16* Kh = Kb + (long)bh * SEQ * HD;
  const u16* Vh = Vt + (long)bh * HD * SEQ;
  const float* mh = mask + h * SEQ;

  // LDS: K [64][128], V [128][64], elem-swizzled (^ (row&7)<<3), + per-wave P
  __shared__ u16 Ks[64 * 128];
  __shared__ u16 Vs[128 * 64];
  __shared__ u16 p_lds[4 * 16 * 64];
  u16* pw = p_lds + w * (16 * 64);

  int krow[4], kcol[4], vrow[4], vcol[4];
#pragma unroll
  for (int i = 0; i < 4; i++) {
    int c = i * 256 + t;
    krow[i] = c >> 4; kcol[i] = (c & 15) * 8;   // K: 64 rows x 128 elems
    vrow[i] = c >> 3; vcol[i] = (c & 7) * 8;    // V: 128 rows x 64 elems
  }

  const float sm_scale = 0.08838834764831845f;  // 1/sqrt(128)

  for (int half = 0; half < 2; half++) {
    int qt = half ? qp : (NT - 1 - qp);  // long half first (warms L2 for short half)
    int q0 = qt * 64 + w * 16;
    int nt = qt + 1;

    bf16x8 qf[4];
#pragma unroll
    for (int kc = 0; kc < 4; kc++)
      qf[kc] = *(const bf16x8*)(Qh + (long)(q0 + l15) * HD + kc * 32 + lhi * 8);

    int rowr[4];
#pragma unroll
    for (int r = 0; r < 4; r++) rowr[r] = q0 + lhi * 4 + r;

    float mrun[4], lrun[4];
    f32x4 oacc[8] = {};
#pragma unroll
    for (int r = 0; r < 4; r++) { mrun[r] = -1e30f; lrun[r] = 0.f; }

    // prologue: stage tile 0 (barrier first: prior half's readers must finish)
    bf16x8 kst[4], vst[4];
#pragma unroll
    for (int i = 0; i < 4; i++) kst[i] = *(const bf16x8*)(Kh + (long)krow[i] * HD + kcol[i]);
#pragma unroll
    for (int i = 0; i < 4; i++) vst[i] = *(const bf16x8*)(Vh + (long)vrow[i] * SEQ + vcol[i]);
    __syncthreads();
#pragma unroll
    for (int i = 0; i < 4; i++)
      *(bf16x8*)(Ks + krow[i] * 128 + (kcol[i] ^ ((krow[i] & 7) << 3))) = kst[i];
#pragma unroll
    for (int i = 0; i < 4; i++)
      *(bf16x8*)(Vs + vrow[i] * 64 + (vcol[i] ^ ((vrow[i] & 7) << 3))) = vst[i];
    __syncthreads();

    for (int kt = 0; kt < nt; kt++) {
      int kb = kt * 64;
      bool have_next = (kt + 1 < nt);
      bool diag = (kt == nt - 1);
      // ---- issue global loads for tile kt+1 (hide HBM latency under compute) ----
      if (have_next) {
        int kb2 = kb + 64;
#pragma unroll
        for (int i = 0; i < 4; i++)
          kst[i] = *(const bf16x8*)(Kh + (long)(kb2 + krow[i]) * HD + kcol[i]);
#pragma unroll
        for (int i = 0; i < 4; i++)
          vst[i] = *(const bf16x8*)(Vh + (long)vrow[i] * SEQ + kb2 + vcol[i]);
      }
      float bvv[4];
#pragma unroll
      for (int cb = 0; cb < 4; cb++) bvv[cb] = mh[kb + cb * 16 + l15];
      // ---- QK^T from LDS ----
      f32x4 sc[4] = {};
      __builtin_amdgcn_s_setprio(1);
#pragma unroll
      for (int kc = 0; kc < 4; kc++)
#pragma unroll
        for (int cb = 0; cb < 4; cb++) {
          int rr = cb * 16 + l15;
          bf16x8 kf = *(const bf16x8*)(Ks + rr * 128 + ((kc * 32 + lhi * 8) ^ ((rr & 7) << 3)));
          sc[cb] = __builtin_amdgcn_mfma_f32_16x16x32_bf16(qf[kc], kf, sc[cb], 0, 0, 0);
        }
      __builtin_amdgcn_s_setprio(0);
      // ---- alibi + causal + running softmax ----
      float p[4][4], tmax[4];
#pragma unroll
      for (int cb = 0; cb < 4; cb++) {
        int col = kb + cb * 16 + l15;
#pragma unroll
        for (int r = 0; r < 4; r++) {
          float v = sc[cb][r] * sm_scale + bvv[cb];
          if (diag) v = (col <= rowr[r]) ? v : -1e30f;
          p[cb][r] = v;
        }
      }
#pragma unroll
      for (int r = 0; r < 4; r++)
        tmax[r] = fmaxf(fmaxf(p[0][r], p[1][r]), fmaxf(p[2][r], p[3][r]));
      float alpha[4];
#pragma unroll
      for (int r = 0; r < 4; r++) {
        float v = tmax[r];
        v = fmaxf(v, __shfl_xor(v, 1));
        v = fmaxf(v, __shfl_xor(v, 2));
        v = fmaxf(v, __shfl_xor(v, 4));
        v = fmaxf(v, __shfl_xor(v, 8));
        float mnew = fmaxf(mrun[r], v);
        alpha[r] = __expf(mrun[r] - mnew);
        mrun[r] = mnew;
        float s = 0.f;
#pragma unroll
        for (int cb = 0; cb < 4; cb++) {
          float e = __expf(p[cb][r] - mnew);
          p[cb][r] = e;
          s += e;
        }
        s += __shfl_xor(s, 1); s += __shfl_xor(s, 2);
        s += __shfl_xor(s, 4); s += __shfl_xor(s, 8);
        lrun[r] = lrun[r] * alpha[r] + s;
      }
#pragma unroll
      for (int nb = 0; nb < 8; nb++)
#pragma unroll
        for (int r = 0; r < 4; r++) oacc[nb][r] *= alpha[r];
      // ---- P -> per-wave LDS (swizzled), wave-local ----
#pragma unroll
      for (int cb = 0; cb < 4; cb++)
#pragma unroll
        for (int r = 0; r < 4; r++) {
          int rr = lhi * 4 + r;
          pw[(rr * 64 + cb * 16 + l15) ^ ((rr & 7) << 3)] = f2bf(p[cb][r]);
        }
      asm volatile("s_waitcnt lgkmcnt(0)" ::: "memory");
      bf16x8 pa0 = *(const bf16x8*)(pw + ((l15 * 64 + lhi * 8) ^ ((l15 & 7) << 3)));
      bf16x8 pa1 = *(const bf16x8*)(pw + ((l15 * 64 + 32 + lhi * 8) ^ ((l15 & 7) << 3)));
      // ---- PV from LDS ----
      __builtin_amdgcn_s_setprio(1);
#pragma unroll
      for (int nb = 0; nb < 8; nb++) {
        int rr = nb * 16 + l15;
        bf16x8 vf0 = *(const bf16x8*)(Vs + rr * 64 + ((lhi * 8) ^ ((rr & 7) << 3)));
        bf16x8 vf1 = *(const bf16x8*)(Vs + rr * 64 + ((32 + lhi * 8) ^ ((rr & 7) << 3)));
        oacc[nb] = __builtin_amdgcn_mfma_f32_16x16x32_bf16(pa0, vf0, oacc[nb], 0, 0, 0);
        oacc[nb] = __builtin_amdgcn_mfma_f32_16x16x32_bf16(pa1, vf1, oacc[nb], 0, 0, 0);
      }
      __builtin_amdgcn_s_setprio(0);
      // ---- single-buffer swap ----
      if (have_next) {
        __syncthreads();
#pragma unroll
        for (int i = 0; i < 4; i++)
          *(bf16x8*)(Ks + krow[i] * 128 + (kcol[i] ^ ((krow[i] & 7) << 3))) = kst[i];
#pragma unroll
        for (int i = 0; i < 4; i++)
          *(bf16x8*)(Vs + vrow[i] * 64 + (vcol[i] ^ ((vrow[i] & 7) << 3))) = vst[i];
        __syncthreads();
      }
    }
#pragma unroll
    for (int nb = 0; nb < 8; nb++)
#pragma unroll
      for (int r = 0; r < 4; r++) {
        int row = q0 + lhi * 4 + r;
        float v = oacc[nb][r] / lrun[r];
        Ao[((long)(b * SEQ + row)) * DM + h * HD + nb * 16 + l15] = f2bf(v);
      }
  }
}

// ---------------- launcher ----------------
extern "C" void kernel_launch(void* const* d_in, const int* in_sizes, int n_in,
                              void* d_out, int out_size, void* d_ws, size_t ws_size,
                              hipStream_t stream) {
  const float* x    = (const float*)d_in[0];
  const float* amsk = (const float*)d_in[1];
  const float* Wqkv = (const float*)d_in[2];
  const float* bqkv = (const float*)d_in[3];
  const float* Wout = (const float*)d_in[4];
  const float* bout = (const float*)d_in[5];
  float* out = (float*)d_out;

  char* ws = (char*)d_ws;
  u16* xb  = (u16*)(ws + 0);                   // [4096][2048]
  u16* WqT = (u16*)(ws + 16777216UL);          // [6144][2048]
  u16* WoT = (u16*)(ws + 41943040UL);          // [2048][2048]
  u16* Qb  = (u16*)(ws + 50331648UL);          // [B*H][S][HD]
  u16* Kb  = (u16*)(ws + 67108864UL);          // [B*H][S][HD]
  u16* Vt  = (u16*)(ws + 83886080UL);          // [B*H][HD][S]
  u16* Ao  = (u16*)(ws + 100663296UL);         // [4096][2048]

  k_cvt<<<8192, 256, 0, stream>>>(x, xb, (MROWS * DM) / 4);
  k_transpose<<<dim3(N3 / 32, DM / 32), 256, 0, stream>>>(Wqkv, WqT, DM, N3);
  k_transpose<<<dim3(DM / 32, DM / 32), 256, 0, stream>>>(Wout, WoT, DM, DM);
  k_gemm_qkv<<<dim3(N3 / 128, MROWS / 128), 256, 0, stream>>>(xb, WqT, bqkv, Qb, Kb, Vt);
  k_attn<<<dim3(SEQ / 128, BATCH * NH), 256, 0, stream>>>(Qb, Kb, Vt, amsk, Ao);
  k_gemm_out<<<dim3(DM / 128, MROWS / 128), 256, 0, stream>>>(Ao, WoT, bout, out);
}